// Round 3
// baseline (499.323 us; speedup 1.0000x reference)
//
#include <hip/hip_runtime.h>
#include <stdint.h>

// B=4,H=8,Lq=512,NB=32,NT=128,D=64. Outputs: out [B,Lq,H*D] then attn_w [B,H,Lq,NB,NT].
constexpr int CB=4, CH=8, CLQ=512, CNB=32, CNT=128, CD=64;
constexpr size_t KVELEMS = (size_t)CB*CNB*CH*CNT*CD;      // 8,388,608
constexpr size_t WS_NEED = KVELEMS * 2 * 3;               // khi, klo, vt (bf16) = 50,331,648 B

typedef __attribute__((ext_vector_type(8))) short short8;
typedef __attribute__((ext_vector_type(4))) float f32x4;

union Frag { uint32_t u[4]; short8 s8; uint4 v; };

__device__ inline uint32_t fb(float x){ union{float f;uint32_t u;} v; v.f=x; return v.u; }
__device__ inline float uf(uint32_t u){ union{float f;uint32_t u;} v; v.u=u; return v.f; }
// pack bf16(trunc) of two floats: [hi16(b) : hi16(a)]
__device__ inline uint32_t packhi(float a, float b){ return (fb(b)&0xffff0000u)|(fb(a)>>16); }
__device__ inline uint32_t lopack(float a, float b){
    float ra = a - uf(fb(a)&0xffff0000u);
    float rb = b - uf(fb(b)&0xffff0000u);
    return packhi(ra, rb);
}
__device__ inline f32x4 mfma_bf16(const Frag& a, const Frag& b, f32x4 c){
    return __builtin_amdgcn_mfma_f32_16x16x32_bf16(a.s8, b.s8, c, 0, 0, 0);
}

// ---------------- Phase 1: K -> bf16 hi/lo, V -> bf16 transposed [d][t] ----------------
__global__ __launch_bounds__(256, 2)
void prep_kernel(const float* __restrict__ kg, const float* __restrict__ vg,
                 ushort* __restrict__ khi, ushort* __restrict__ klo, ushort* __restrict__ vt)
{
    __shared__ float vtile[64 * 132];     // [d][t] f32, stride 132 dwords
    const int tid = threadIdx.x;
    const size_t base = (size_t)blockIdx.x * (CNT*CD);   // one (b,n,h) slice of 8192

    // K -> hi/lo bf16 (same layout as K)
    const float4* kb4 = (const float4*)(kg + base);
    uint2* kh2 = (uint2*)(khi + base);
    uint2* kl2 = (uint2*)(klo + base);
    #pragma unroll
    for (int j = 0; j < 8; ++j) {
        int i4 = j*256 + tid;
        float4 f = kb4[i4];
        kh2[i4] = make_uint2(packhi(f.x,f.y), packhi(f.z,f.w));
        kl2[i4] = make_uint2(lopack(f.x,f.y), lopack(f.z,f.w));
    }

    // V stage transposed into LDS
    const float4* vb4 = (const float4*)(vg + base);
    #pragma unroll
    for (int it = 0; it < 8; ++it) {
        int flat = it*256 + tid;          // 0..2047 float4s
        int t = flat >> 4, dg = flat & 15;
        float4 f = vb4[t*16 + dg];
        vtile[(dg*4+0)*132 + t] = f.x;
        vtile[(dg*4+1)*132 + t] = f.y;
        vtile[(dg*4+2)*132 + t] = f.z;
        vtile[(dg*4+3)*132 + t] = f.w;
    }
    __syncthreads();

    // write vt[d][t] bf16, fully coalesced
    {
        int d = tid >> 2, tq = tid & 3;
        float fv[32];
        #pragma unroll
        for (int c = 0; c < 8; ++c) {
            f32x4 r = *(const f32x4*)&vtile[d*132 + tq*32 + c*4];
            fv[c*4+0]=r[0]; fv[c*4+1]=r[1]; fv[c*4+2]=r[2]; fv[c*4+3]=r[3];
        }
        uint4* dst = (uint4*)(vt + base + d*CNT + tq*32);
        #pragma unroll
        for (int j = 0; j < 4; ++j) {
            uint4 o;
            o.x = packhi(fv[j*8+0], fv[j*8+1]);
            o.y = packhi(fv[j*8+2], fv[j*8+3]);
            o.z = packhi(fv[j*8+4], fv[j*8+5]);
            o.w = packhi(fv[j*8+6], fv[j*8+7]);
            dst[j] = o;
        }
    }
}

// ---------------- Phase 2: barrier-free attention ----------------
// Grid 1024: wave w of each wg handles n in [8w, 8w+8) for the wg's 16 q-rows.
__global__ __launch_bounds__(256, 4)
void attn_kernel(const float* __restrict__ qg, const ushort* __restrict__ khig,
                 const ushort* __restrict__ klog, const ushort* __restrict__ vtg,
                 const float* __restrict__ sg, float* __restrict__ outg,
                 float* __restrict__ awg)
{
    __shared__ float pbuf[4][16*36];   // per-wave P kc-chunk (16 rows x 32 tok), stride 36
    __shared__ float obuf[4][16*68];   // final cross-wave O reduction

    const int tid  = threadIdx.x;
    const int wave = tid >> 6, lane = tid & 63;
    const int l15  = lane & 15, q8 = lane >> 4;

    // XCD swizzle: all 32 wgs of one bh land on XCD bh>>2
    const int bid = blockIdx.x;
    const int kk  = bid >> 3;
    const int bh  = (bid & 7)*4 + (kk & 3);
    const int qt  = kk >> 2;
    const int b   = bh >> 3, h = bh & 7;
    const int q0  = qt * 16;

    // Q A-fragments (rows m=l15, k = s*32 + q8*8 + j), pre-scaled, hi/lo split
    Frag qhi[2], qlo[2];
    {
        const float* qrow = qg + ((size_t)bh*CLQ + q0 + l15)*CD;
        #pragma unroll
        for (int s = 0; s < 2; ++s) {
            f32x4 a = *(const f32x4*)&qrow[s*32 + q8*8];
            f32x4 c = *(const f32x4*)&qrow[s*32 + q8*8 + 4];
            float e[8] = {a[0]*0.125f, a[1]*0.125f, a[2]*0.125f, a[3]*0.125f,
                          c[0]*0.125f, c[1]*0.125f, c[2]*0.125f, c[3]*0.125f};
            #pragma unroll
            for (int p = 0; p < 4; ++p) {
                qhi[s].u[p] = packhi(e[2*p], e[2*p+1]);
                qlo[s].u[p] = lopack(e[2*p], e[2*p+1]);
            }
        }
    }

    f32x4 O[4];
    #pragma unroll
    for (int cd = 0; cd < 4; ++cd) O[cd] = (f32x4){0.f,0.f,0.f,0.f};

    float* pw = pbuf[wave];
    const int n0 = wave * 8;

    for (int nn = 0; nn < 8; ++nn) {
        const int n = n0 + nn;
        const size_t sb = (size_t)((b*CNB + n)*CH + h) * (CNT*CD);
        const ushort* kh = khig + sb;
        const ushort* kl = klog + sb;
        const ushort* vb = vtg  + sb;

        // ---- QK^T: 8 chunks of 16 tokens; B-frags straight from global ----
        f32x4 E[8];
        #pragma unroll
        for (int c = 0; c < 8; ++c) {
            const ushort* kr = kh + (c*16 + l15)*CD + q8*8;
            const ushort* lr = kl + (c*16 + l15)*CD + q8*8;
            Frag kh0, kh1, kl0, kl1;
            kh0.v = *(const uint4*)(kr);
            kh1.v = *(const uint4*)(kr + 32);
            kl0.v = *(const uint4*)(lr);
            kl1.v = *(const uint4*)(lr + 32);
            f32x4 accA = (f32x4){0.f,0.f,0.f,0.f};
            f32x4 accB = (f32x4){0.f,0.f,0.f,0.f};
            accA = mfma_bf16(qhi[0], kh0, accA);
            accB = mfma_bf16(qlo[0], kh0, accB);
            accA = mfma_bf16(qhi[1], kh1, accA);
            accB = mfma_bf16(qlo[1], kh1, accB);
            accA = mfma_bf16(qhi[0], kl0, accA);
            accB = mfma_bf16(qhi[1], kl1, accB);
            E[c] = accA + accB;
        }

        // ---- exp + wave-local row sums (tokens live on l15 only) ----
        float ps[4] = {0.f,0.f,0.f,0.f};
        #pragma unroll
        for (int c = 0; c < 8; ++c) {
            #pragma unroll
            for (int r = 0; r < 4; ++r) { E[c][r] = __expf(E[c][r]); ps[r] += E[c][r]; }
        }
        #pragma unroll
        for (int off = 1; off <= 8; off <<= 1) {
            #pragma unroll
            for (int r = 0; r < 4; ++r) ps[r] += __shfl_xor(ps[r], off, 64);
        }
        float fac[4];
        const float* srow = sg + ((size_t)bh*CLQ + q0 + q8*4)*CNB + n;
        #pragma unroll
        for (int r = 0; r < 4; ++r) fac[r] = srow[r*CNB] / ps[r];

        // ---- per-32-token chunk: attn_w store + P C->A via tiny LDS + PV ----
        #pragma unroll
        for (int kc = 0; kc < 4; ++kc) {
            #pragma unroll
            for (int r = 0; r < 4; ++r) {
                float p0 = E[kc*2][r]   * fac[r];
                float p1 = E[kc*2+1][r] * fac[r];
                pw[(q8*4+r)*36 + l15]      = p0;
                pw[(q8*4+r)*36 + 16 + l15] = p1;
                float* ab = awg + (((size_t)bh*CLQ + q0 + q8*4 + r)*CNB + n)*CNT + kc*32 + l15;
                ab[0]  = p0;
                ab[16] = p1;
            }
            Frag pf;   // A-layout: row=l15, k=q8*8+j (in-order DS per wave makes this safe)
            {
                f32x4 a = *(const f32x4*)&pw[l15*36 + q8*8];
                f32x4 c = *(const f32x4*)&pw[l15*36 + q8*8 + 4];
                pf.u[0] = packhi(a[0],a[1]); pf.u[1] = packhi(a[2],a[3]);
                pf.u[2] = packhi(c[0],c[1]); pf.u[3] = packhi(c[2],c[3]);
            }
            #pragma unroll
            for (int cd = 0; cd < 4; ++cd) {
                Frag vf;   // B[k=token][n=d]: 8 consecutive tokens from vt[d][t]
                vf.v = *(const uint4*)&vb[(cd*16 + l15)*CNT + kc*32 + q8*8];
                O[cd] = mfma_bf16(pf, vf, O[cd]);
            }
        }
    }

    // ---- cross-wave O reduction (waves hold disjoint n-ranges) ----
    {
        float* ow = obuf[wave];
        #pragma unroll
        for (int cd = 0; cd < 4; ++cd)
            #pragma unroll
            for (int r = 0; r < 4; ++r)
                ow[(q8*4 + r)*68 + cd*16 + l15] = O[cd][r];
    }
    __syncthreads();
    {
        int r = tid >> 4, dq = tid & 15;
        f32x4 acc = (f32x4){0.f,0.f,0.f,0.f};
        #pragma unroll
        for (int wv = 0; wv < 4; ++wv)
            acc += *(const f32x4*)&obuf[wv][r*68 + dq*4];
        *(f32x4*)&outg[((size_t)b*CLQ + q0 + r)*(CH*CD) + h*CD + dq*4] = acc;
    }
}

// ---------------- Fallback (round-2 kernel) if ws too small ----------------
constexpr int PSTR=36, OSTR=68;
__global__ __launch_bounds__(256, 4)
void sdpa_fallback_kernel(const float* __restrict__ qg, const float* __restrict__ kg,
                          const float* __restrict__ vg, const float* __restrict__ sg,
                          float* __restrict__ outg, float* __restrict__ awg)
{
    __shared__ float pbuf[4 * 16 * PSTR];
    __shared__ float sums[2][64];
    __shared__ float as_t[CNB * 16];
    __shared__ float obuf[4 * 16 * OSTR];

    const int tid = threadIdx.x, wave = tid>>6, lane = tid&63;
    const int l15 = lane&15, q8 = lane>>4;
    const int bid = blockIdx.x, qt = bid&31, bh = bid>>5, b = bh>>3, h = bh&7;
    const int q0 = qt*16;

    {
        const float* sbase = sg + ((size_t)bh*CLQ + q0)*CNB;
        #pragma unroll
        for (int e = 0; e < 2; ++e) {
            int idx = tid + e*256; int r = idx>>5, n = idx&31;
            as_t[n*16 + r] = sbase[r*CNB + n];
        }
    }
    Frag qhi[2], qlo[2];
    {
        const float* qrow = qg + ((size_t)bh*CLQ + q0 + l15)*CD;
        #pragma unroll
        for (int s = 0; s < 2; ++s) {
            f32x4 a = *(const f32x4*)&qrow[s*32 + q8*8];
            f32x4 c = *(const f32x4*)&qrow[s*32 + q8*8 + 4];
            float e[8] = {a[0]*0.125f,a[1]*0.125f,a[2]*0.125f,a[3]*0.125f,
                          c[0]*0.125f,c[1]*0.125f,c[2]*0.125f,c[3]*0.125f};
            #pragma unroll
            for (int p = 0; p < 4; ++p) {
                qhi[s].u[p] = packhi(e[2*p], e[2*p+1]);
                qlo[s].u[p] = lopack(e[2*p], e[2*p+1]);
            }
        }
    }
    f32x4 O[4];
    #pragma unroll
    for (int cd = 0; cd < 4; ++cd) O[cd] = (f32x4){0.f,0.f,0.f,0.f};
    float* pw = &pbuf[wave * 16 * PSTR];

    for (int n = 0; n < CNB; ++n) {
        const float* kb = kg + ((size_t)((b*CNB + n)*CH + h))*CNT*CD;
        const float* vb = vg + ((size_t)((b*CNB + n)*CH + h))*CNT*CD + wave*32*CD;
        f32x4 S[2];
        #pragma unroll
        for (int c = 0; c < 2; ++c) {
            const float* kr = kb + (size_t)(wave*32 + c*16 + l15)*CD;
            Frag khA[2], klA[2];
            #pragma unroll
            for (int s = 0; s < 2; ++s) {
                f32x4 a = *(const f32x4*)&kr[s*32 + q8*8];
                f32x4 d = *(const f32x4*)&kr[s*32 + q8*8 + 4];
                float e[8] = {a[0],a[1],a[2],a[3],d[0],d[1],d[2],d[3]};
                #pragma unroll
                for (int p = 0; p < 4; ++p) {
                    khA[s].u[p] = packhi(e[2*p], e[2*p+1]);
                    klA[s].u[p] = lopack(e[2*p], e[2*p+1]);
                }
            }
            f32x4 acc = (f32x4){0.f,0.f,0.f,0.f};
            acc = mfma_bf16(qhi[0], khA[0], acc);
            acc = mfma_bf16(qhi[1], khA[1], acc);
            acc = mfma_bf16(qlo[0], khA[0], acc);
            acc = mfma_bf16(qlo[1], khA[1], acc);
            acc = mfma_bf16(qhi[0], klA[0], acc);
            acc = mfma_bf16(qhi[1], klA[1], acc);
            S[c] = acc;
        }
        float E0[4], E1[4], ps[4];
        #pragma unroll
        for (int r = 0; r < 4; ++r) { E0[r]=__expf(S[0][r]); E1[r]=__expf(S[1][r]); ps[r]=E0[r]+E1[r]; }
        #pragma unroll
        for (int off = 1; off <= 8; off <<= 1)
            #pragma unroll
            for (int r = 0; r < 4; ++r) ps[r] += __shfl_xor(ps[r], off, 64);
        if (l15 == 0) { f32x4 t = {ps[0],ps[1],ps[2],ps[3]}; *(f32x4*)&sums[n&1][wave*16 + q8*4] = t; }
        __syncthreads();
        f32x4 d4 = (f32x4){0.f,0.f,0.f,0.f};
        #pragma unroll
        for (int wv = 0; wv < 4; ++wv) d4 += *(const f32x4*)&sums[n&1][wv*16 + q8*4];
        const f32x4 asv = *(const f32x4*)&as_t[n*16 + q8*4];
        float fac[4];
        #pragma unroll
        for (int r = 0; r < 4; ++r) fac[r] = asv[r] / d4[r];
        #pragma unroll
        for (int r = 0; r < 4; ++r) {
            pw[(q8*4+r)*PSTR + l15]      = E0[r]*fac[r];
            pw[(q8*4+r)*PSTR + 16 + l15] = E1[r]*fac[r];
        }
        #pragma unroll
        for (int i = 0; i < 2; ++i) {
            int idx = lane + i*64; int row = idx>>3, c4 = idx&7;
            f32x4 pv = *(const f32x4*)&pw[row*PSTR + c4*4];
            *(f32x4*)&awg[(((size_t)bh*CLQ + q0 + row)*CNB + n)*CNT + wave*32 + c4*4] = pv;
        }
        Frag phi;
        {
            f32x4 a = *(const f32x4*)&pw[l15*PSTR + q8*8];
            f32x4 c = *(const f32x4*)&pw[l15*PSTR + q8*8 + 4];
            phi.u[0]=packhi(a[0],a[1]); phi.u[1]=packhi(a[2],a[3]);
            phi.u[2]=packhi(c[0],c[1]); phi.u[3]=packhi(c[2],c[3]);
        }
        #pragma unroll
        for (int cd = 0; cd < 4; ++cd) {
            float vf[8];
            #pragma unroll
            for (int j = 0; j < 8; ++j) vf[j] = vb[(q8*8 + j)*CD + cd*16 + l15];
            Frag vh;
            #pragma unroll
            for (int p = 0; p < 4; ++p) vh.u[p] = packhi(vf[2*p], vf[2*p+1]);
            O[cd] = mfma_bf16(phi, vh, O[cd]);
        }
    }
    {
        float* ow = &obuf[wave * 16 * OSTR];
        #pragma unroll
        for (int cd = 0; cd < 4; ++cd)
            #pragma unroll
            for (int r = 0; r < 4; ++r)
                ow[(q8*4 + r)*OSTR + cd*16 + l15] = O[cd][r];
    }
    __syncthreads();
    {
        int r = tid >> 4, dq = tid & 15;
        f32x4 acc = (f32x4){0.f,0.f,0.f,0.f};
        #pragma unroll
        for (int wv = 0; wv < 4; ++wv) acc += *(const f32x4*)&obuf[wv*16*OSTR + r*OSTR + dq*4];
        *(f32x4*)&outg[((size_t)b*CLQ + q0 + r)*(CH*CD) + h*CD + dq*4] = acc;
    }
}

extern "C" void kernel_launch(void* const* d_in, const int* in_sizes, int n_in,
                              void* d_out, int out_size, void* d_ws, size_t ws_size,
                              hipStream_t stream) {
    const float* q = (const float*)d_in[0];
    const float* k = (const float*)d_in[1];
    const float* v = (const float*)d_in[2];
    const float* s = (const float*)d_in[3];
    float* out = (float*)d_out;
    float* aw  = out + (size_t)CB * CLQ * CH * CD;

    if (ws_size >= WS_NEED) {
        ushort* khi = (ushort*)d_ws;
        ushort* klo = khi + KVELEMS;
        ushort* vt  = klo + KVELEMS;
        prep_kernel<<<CB*CNB*CH, 256, 0, stream>>>(k, v, khi, klo, vt);
        attn_kernel<<<1024, 256, 0, stream>>>(q, khi, klo, vt, s, out, aw);
    } else {
        sdpa_fallback_kernel<<<1024, 256, 0, stream>>>(q, k, v, s, out, aw);
    }
}